// Round 1
// baseline (455.050 us; speedup 1.0000x reference)
//
#include <hip/hip_runtime.h>
#include <math.h>

// Problem constants (match reference)
#define B_    8192
#define F_    64
#define V_    1000
#define E_    64
#define T_    2
#define NTOK_ 16
#define G_    4
#define D_    256
#define K_    128   // T*E
#define LN_EPS 1e-5f

// One block per batch row b. 256 threads = 4 waves.
// Phase 1: gather+pool -> x[16][128] in LDS (coalesced 256B rows per wave)
// Phase 2: thread d computes h[n][d] = silu(x[n]·W[d] + b[d]) for all 16 tokens
// Phase 3: one wave per 4 tokens: shuffle-reduce LayerNorm, coalesced store
__global__ __launch_bounds__(256) void fused_tokenizer_kernel(
    const int*   __restrict__ int_feats,     // (B, F)
    const int*   __restrict__ missing_mask,  // (B, F)
    const int*   __restrict__ group_idx,     // (NTOK, G)
    const float* __restrict__ emb_tables,    // (T, F, V, E)
    const float* __restrict__ missing_emb,   // (T, F, E)
    const float* __restrict__ W,             // (D, K)
    const float* __restrict__ bias,          // (D,)
    const float* __restrict__ gamma,         // (D,)
    const float* __restrict__ beta,          // (D,)
    float*       __restrict__ out)           // (B, NTOK, D)
{
    __shared__ float xs[NTOK_][K_];   // 8 KB
    __shared__ float hs[NTOK_][D_];   // 16 KB
    __shared__ int   sid[F_];
    __shared__ int   smask[F_];
    __shared__ int   sg[NTOK_ * G_];

    const int tid = threadIdx.x;
    const int b   = blockIdx.x;

    if (tid < F_) {
        sid[tid]   = int_feats[b * F_ + tid];
        smask[tid] = missing_mask[b * F_ + tid];
        sg[tid]    = group_idx[tid];   // NTOK*G == F == 64
    }
    __syncthreads();

    // ---- Phase 1: gather + mean-pool into xs ----
    // element j = i*256 + tid ; n = j>>7 ; r = j&127 ; t = r>>6 ; e = r&63
    // Each wave (64 lanes) reads one contiguous 256B embedding row per gather.
#pragma unroll
    for (int i = 0; i < 8; ++i) {
        const int j = i * 256 + tid;
        const int n = j >> 7;
        const int r = j & 127;
        const int t = r >> 6;
        const int e = r & 63;
        float acc = 0.f;
#pragma unroll
        for (int g = 0; g < G_; ++g) {
            const int f  = sg[n * G_ + g];
            const int id = sid[f];
            float v = emb_tables[(((size_t)(t * F_ + f) * V_) + id) * E_ + e];
            if (smask[f]) v += missing_emb[(t * F_ + f) * E_ + e];
            acc += v;
        }
        xs[n][r] = 0.25f * acc;
    }
    __syncthreads();

    // ---- Phase 2: linear + SiLU ----
    // Thread d = tid owns output feature d across all 16 tokens.
    // W row d read once (L1 line reuse across k-chunks); x reads are LDS broadcasts.
    {
        const int d = tid;
        float acc[NTOK_];
#pragma unroll
        for (int n = 0; n < NTOK_; ++n) acc[n] = 0.f;

        for (int k = 0; k < K_; k += 4) {
            const float4 w4 = *(const float4*)(&W[(size_t)d * K_ + k]);
#pragma unroll
            for (int n = 0; n < NTOK_; ++n) {
                const float4 x4 = *(const float4*)(&xs[n][k]);
                acc[n] += w4.x * x4.x + w4.y * x4.y + w4.z * x4.z + w4.w * x4.w;
            }
        }
        const float bd = bias[d];
#pragma unroll
        for (int n = 0; n < NTOK_; ++n) {
            const float z = acc[n] + bd;
            hs[n][d] = z / (1.f + __expf(-z));   // silu
        }
    }
    __syncthreads();

    // ---- Phase 3: LayerNorm over D=256 per token; wave w handles tokens 4w..4w+3 ----
    {
        const int wave = tid >> 6;
        const int lane = tid & 63;
#pragma unroll
        for (int q = 0; q < 4; ++q) {
            const int n = wave * 4 + q;
            const float v0 = hs[n][lane];
            const float v1 = hs[n][lane + 64];
            const float v2 = hs[n][lane + 128];
            const float v3 = hs[n][lane + 192];
            float s  = v0 + v1 + v2 + v3;
            float ss = v0 * v0 + v1 * v1 + v2 * v2 + v3 * v3;
#pragma unroll
            for (int off = 32; off > 0; off >>= 1) {
                s  += __shfl_down(s,  off, 64);
                ss += __shfl_down(ss, off, 64);
            }
            s  = __shfl(s,  0, 64);
            ss = __shfl(ss, 0, 64);
            const float mu   = s * (1.f / D_);
            const float var  = ss * (1.f / D_) - mu * mu;
            const float rsig = rsqrtf(var + LN_EPS);

            const size_t obase = ((size_t)b * NTOK_ + n) * D_;
#pragma unroll
            for (int c = 0; c < 4; ++c) {
                const int dd = lane + c * 64;
                const float h = (c == 0) ? v0 : (c == 1) ? v1 : (c == 2) ? v2 : v3;
                out[obase + dd] = (h - mu) * rsig * gamma[dd] + beta[dd];
            }
        }
    }
}

extern "C" void kernel_launch(void* const* d_in, const int* in_sizes, int n_in,
                              void* d_out, int out_size, void* d_ws, size_t ws_size,
                              hipStream_t stream) {
    const int*   int_feats    = (const int*)  d_in[0];
    const int*   missing_mask = (const int*)  d_in[1];
    const int*   group_idx    = (const int*)  d_in[2];
    const float* emb_tables   = (const float*)d_in[3];
    const float* missing_emb  = (const float*)d_in[4];
    const float* W            = (const float*)d_in[5];
    const float* bias         = (const float*)d_in[6];
    const float* gamma        = (const float*)d_in[7];
    const float* beta         = (const float*)d_in[8];
    float* out = (float*)d_out;

    fused_tokenizer_kernel<<<B_, 256, 0, stream>>>(
        int_feats, missing_mask, group_idx, emb_tables, missing_emb,
        W, bias, gamma, beta, out);
}

// Round 2
// 241.953 us; speedup vs baseline: 1.8807x; 1.8807x over previous
//
#include <hip/hip_runtime.h>
#include <math.h>

// Problem constants (match reference)
#define B_    8192
#define F_    64
#define V_    1000
#define E_    64
#define T_    2
#define NTOK_ 16
#define G_    4
#define D_    256
#define K_    128   // T*E
#define LN_EPS 1e-5f

#define XSP   136   // xs row stride in bf16 elements (128 + 8 pad: even bank spread for b128 frag reads)
#define HSP   260   // hs row stride in floats (256 + 4: keeps float4 alignment, 2-way-max banks)

typedef __attribute__((ext_vector_type(8))) short  frag_ab;  // 8 bf16 = 4 VGPRs
typedef __attribute__((ext_vector_type(4))) float  frag_cd;  // 4 fp32 acc

static __device__ __forceinline__ unsigned short f2bf(float f) {
    // round-to-nearest-even fp32 -> bf16 (values are finite here)
    unsigned int u = __float_as_uint(f);
    u += 0x7FFFu + ((u >> 16) & 1u);
    return (unsigned short)(u >> 16);
}

// ---- prologue: W fp32 (D,K) -> bf16 in workspace (row-major, same layout) ----
__global__ __launch_bounds__(256) void convert_w_kernel(const float* __restrict__ W,
                                                        unsigned int* __restrict__ Wb_packed) {
    const int i = blockIdx.x * 256 + threadIdx.x;   // one uint = 2 bf16
    if (i < (D_ * K_) / 2) {
        const float2 v = *(const float2*)(W + (size_t)i * 2);
        Wb_packed[i] = (unsigned int)f2bf(v.x) | ((unsigned int)f2bf(v.y) << 16);
    }
}

// One block per batch row b. 256 threads = 4 waves.
// Phase 1: float4 gather + mean-pool -> xs[16][128] bf16 in LDS
// Phase 2: MFMA 16x16x32 bf16: x(16x128) @ W^T(128x256) -> silu -> hs in LDS
// Phase 3: one wave per 4 tokens: shuffle-reduce LayerNorm, float4 stores
__global__ __launch_bounds__(256) void fused_tokenizer_kernel(
    const int*   __restrict__ int_feats,     // (B, F)
    const int*   __restrict__ missing_mask,  // (B, F)
    const int*   __restrict__ group_idx,     // (NTOK, G)
    const float* __restrict__ emb_tables,    // (T, F, V, E)
    const float* __restrict__ missing_emb,   // (T, F, E)
    const unsigned short* __restrict__ Wb,   // (D, K) bf16
    const float* __restrict__ bias,          // (D,)
    const float* __restrict__ gamma,         // (D,)
    const float* __restrict__ beta,          // (D,)
    float*       __restrict__ out)           // (B, NTOK, D)
{
    __shared__ unsigned short xs[NTOK_][XSP];  // 4.3 KB, bf16 activations
    __shared__ float          hs[NTOK_][HSP];  // 16.6 KB, post-silu
    __shared__ int   sid[F_];
    __shared__ int   smask[F_];
    __shared__ int   sg[NTOK_ * G_];

    const int tid  = threadIdx.x;
    const int b    = blockIdx.x;
    const int lane = tid & 63;
    const int wave = tid >> 6;

    if (tid < F_) {
        sid[tid]   = int_feats[b * F_ + tid];
        smask[tid] = missing_mask[b * F_ + tid];
        sg[tid]    = group_idx[tid];   // NTOK*G == F == 64
    }
    __syncthreads();

    // ---- Phase 1: gather + mean-pool (float4 granularity) ----
    // chunk c in [0,512): n = c>>5 (token), r4 = c&31, t = r4>>4, e = (r4&15)*4
    // 16 consecutive lanes cover one 256B embedding row -> coalesced dwordx4.
#pragma unroll
    for (int i = 0; i < 2; ++i) {
        const int c  = i * 256 + tid;
        const int n  = c >> 5;
        const int r4 = c & 31;
        const int t  = r4 >> 4;
        const int e  = (r4 & 15) * 4;
        float ax = 0.f, ay = 0.f, az = 0.f, aw = 0.f;
#pragma unroll
        for (int g = 0; g < G_; ++g) {
            const int f  = sg[n * G_ + g];
            const int id = sid[f];
            const float4 v = *(const float4*)(emb_tables + (((size_t)(t * F_ + f) * V_) + id) * E_ + e);
            float vx = v.x, vy = v.y, vz = v.z, vw = v.w;
            if (smask[f]) {
                const float4 mv = *(const float4*)(missing_emb + (size_t)(t * F_ + f) * E_ + e);
                vx += mv.x; vy += mv.y; vz += mv.z; vw += mv.w;
            }
            ax += vx; ay += vy; az += vz; aw += vw;
        }
        union { unsigned int u[2]; } pk;
        pk.u[0] = (unsigned int)f2bf(0.25f * ax) | ((unsigned int)f2bf(0.25f * ay) << 16);
        pk.u[1] = (unsigned int)f2bf(0.25f * az) | ((unsigned int)f2bf(0.25f * aw) << 16);
        *(uint2*)(&xs[n][r4 * 4]) = make_uint2(pk.u[0], pk.u[1]);
    }
    __syncthreads();

    // ---- Phase 2: MFMA 16x16x32 bf16 ----
    // A = x: lane holds A[m=lane&15][k=quad*8+j]; B = W rows (B^T storage):
    // lane holds W[n=nbase+(lane&15)][k=quad*8+j]; D: col(n)=lane&15, row(m)=quad*4+reg.
    {
        const int mA = lane & 15;
        const int q  = lane >> 4;

        frag_ab a[4];
#pragma unroll
        for (int s = 0; s < 4; ++s)
            a[s] = *(const frag_ab*)(&xs[mA][32 * s + 8 * q]);

#pragma unroll
        for (int t = 0; t < 4; ++t) {
            const int nb   = wave * 64 + t * 16;
            const int nrow = nb + mA;
            const unsigned short* wp = Wb + (size_t)nrow * K_ + 8 * q;

            frag_cd acc = {0.f, 0.f, 0.f, 0.f};
#pragma unroll
            for (int s = 0; s < 4; ++s) {
                const frag_ab bfr = *(const frag_ab*)(wp + 32 * s);
                acc = __builtin_amdgcn_mfma_f32_16x16x32_bf16(a[s], bfr, acc, 0, 0, 0);
            }
            const float bn = bias[nrow];
#pragma unroll
            for (int reg = 0; reg < 4; ++reg) {
                const int tok = q * 4 + reg;
                const float z = acc[reg] + bn;
                hs[tok][nrow] = z / (1.f + __expf(-z));   // silu
            }
        }
    }
    __syncthreads();

    // ---- Phase 3: LayerNorm over D=256 per token; wave w handles tokens 4w..4w+3 ----
    {
#pragma unroll
        for (int qq = 0; qq < 4; ++qq) {
            const int n = wave * 4 + qq;
            const float4 v = *(const float4*)(&hs[n][lane * 4]);
            float s  = v.x + v.y + v.z + v.w;
            float ss = v.x * v.x + v.y * v.y + v.z * v.z + v.w * v.w;
#pragma unroll
            for (int off = 32; off > 0; off >>= 1) {
                s  += __shfl_down(s,  off, 64);
                ss += __shfl_down(ss, off, 64);
            }
            s  = __shfl(s,  0, 64);
            ss = __shfl(ss, 0, 64);
            const float mu   = s * (1.f / D_);
            const float var  = ss * (1.f / D_) - mu * mu;
            const float rsig = rsqrtf(var + LN_EPS);

            const float4 gm = *(const float4*)(gamma + lane * 4);
            const float4 bt = *(const float4*)(beta  + lane * 4);
            float4 o;
            o.x = (v.x - mu) * rsig * gm.x + bt.x;
            o.y = (v.y - mu) * rsig * gm.y + bt.y;
            o.z = (v.z - mu) * rsig * gm.z + bt.z;
            o.w = (v.w - mu) * rsig * gm.w + bt.w;
            *(float4*)(out + ((size_t)b * NTOK_ + n) * D_ + lane * 4) = o;
        }
    }
}

extern "C" void kernel_launch(void* const* d_in, const int* in_sizes, int n_in,
                              void* d_out, int out_size, void* d_ws, size_t ws_size,
                              hipStream_t stream) {
    const int*   int_feats    = (const int*)  d_in[0];
    const int*   missing_mask = (const int*)  d_in[1];
    const int*   group_idx    = (const int*)  d_in[2];
    const float* emb_tables   = (const float*)d_in[3];
    const float* missing_emb  = (const float*)d_in[4];
    const float* W            = (const float*)d_in[5];
    const float* bias         = (const float*)d_in[6];
    const float* gamma        = (const float*)d_in[7];
    const float* beta         = (const float*)d_in[8];
    float* out = (float*)d_out;

    unsigned short* Wb = (unsigned short*)d_ws;   // 64 KB bf16 copy of W

    convert_w_kernel<<<(D_ * K_ / 2 + 255) / 256, 256, 0, stream>>>(W, (unsigned int*)Wb);
    fused_tokenizer_kernel<<<B_, 256, 0, stream>>>(
        int_feats, missing_mask, group_idx, emb_tables, missing_emb,
        Wb, bias, gamma, beta, out);
}